// Round 1
// baseline (418.138 us; speedup 1.0000x reference)
//
#include <hip/hip_runtime.h>
#include <stdint.h>

// DPS_55336358642719
// in[0]: x_high  (8,3,1024,1024) f32
// in[1]: scores  (8,16,16)       f32
// out:   patches (128,3,128,128) f32
//
// ws layout: counts[8][16][256] as uint32  (131072 bytes)

#define NSAMP 500
#define DDIM  256

// ---------------- threefry2x32 (JAX-exact) ----------------
__device__ __forceinline__ void threefry2x32_0_42(uint32_t x0, uint32_t x1,
                                                  uint32_t& o0, uint32_t& o1) {
  const uint32_t k0 = 0u, k1 = 42u;
  const uint32_t k2 = k0 ^ k1 ^ 0x1BD11BDAu;
  x0 += k0; x1 += k1;
#define TF_ROUND(r) { x0 += x1; x1 = (x1 << (r)) | (x1 >> (32 - (r))); x1 ^= x0; }
  TF_ROUND(13) TF_ROUND(15) TF_ROUND(26) TF_ROUND(6)
  x0 += k1; x1 += k2 + 1u;
  TF_ROUND(17) TF_ROUND(29) TF_ROUND(16) TF_ROUND(24)
  x0 += k2; x1 += k0 + 2u;
  TF_ROUND(13) TF_ROUND(15) TF_ROUND(26) TF_ROUND(6)
  x0 += k0; x1 += k1 + 3u;
  TF_ROUND(17) TF_ROUND(29) TF_ROUND(16) TF_ROUND(24)
  x0 += k1; x1 += k2 + 4u;
  TF_ROUND(13) TF_ROUND(15) TF_ROUND(26) TF_ROUND(6)
  x0 += k2; x1 += k0 + 5u;
#undef TF_ROUND
  o0 = x0; o1 = x1;
}

// XLA's ErfInv32 (Giles polynomial), fp-contract off for fidelity
__device__ __forceinline__ float xla_erfinv(float x) {
#pragma clang fp contract(off)
  float w = -log1pf(-x * x);
  float p;
  if (w < 5.0f) {
    w = w - 2.5f;
    p = 2.81022636e-08f;
    p = 3.43273939e-07f + p * w;
    p = -3.5233877e-06f + p * w;
    p = -4.39150654e-06f + p * w;
    p = 0.00021858087f + p * w;
    p = -0.00125372503f + p * w;
    p = -0.00417768164f + p * w;
    p = 0.246640727f + p * w;
    p = 1.50140941f + p * w;
  } else {
    w = sqrtf(w) - 3.0f;
    p = -0.000200214257f;
    p = 0.000100950558f + p * w;
    p = 0.00134934322f + p * w;
    p = -0.00367342844f + p * w;
    p = 0.00573950773f + p * w;
    p = -0.0076224613f + p * w;
    p = 0.00943887047f + p * w;
    p = 1.00167406f + p * w;
    p = 2.83297682f + p * w;
  }
  return p * x;
}

__global__ void zero_counts(uint32_t* __restrict__ p, int n) {
  int i = blockIdx.x * blockDim.x + threadIdx.x;
  if (i < n) p[i] = 0u;
}

// One thread = one sample. Computes JAX noise on the fly, keeps a register
// top-16 (sorted ascending by value), then increments counts[b][rank][idx].
__global__ void __launch_bounds__(64) topk_kernel(const float* __restrict__ scores,
                                                  uint32_t* __restrict__ counts) {
#pragma clang fp contract(off)
  int gs = blockIdx.x * 64 + threadIdx.x;
  if (gs >= 8 * NSAMP) return;
  int b = gs / NSAMP;
  int n = gs - b * NSAMP;

  const float* sc = scores + b * DDIM;
  float mn = sc[0], mx = sc[0];
  for (int d = 1; d < DDIM; ++d) {
    float v = sc[d];
    mn = fminf(mn, v);
    mx = fmaxf(mx, v);
  }
  float denom = (mx - mn) + 1e-5f;

  // flat noise index base for (b, n, 0)
  uint32_t base = (uint32_t)(b * (NSAMP * DDIM) + n * DDIM);

  float v[16];
  int ix[16];
#pragma unroll
  for (int t = 0; t < 16; ++t) { v[t] = -INFINITY; ix[t] = -1; }

  const float lo = -0.99999994f;  // nextafter(-1,0) in f32
  for (int d = 0; d < DDIM; ++d) {
    uint32_t j = base + (uint32_t)d;
    // jax_threefry_partitionable=True scheme: 64-bit iota -> (hi=0, lo=j),
    // 32-bit draw = o0 ^ o1
    uint32_t o0, o1;
    threefry2x32_0_42(0u, j, o0, o1);
    uint32_t bits = o0 ^ o1;

    float f = __uint_as_float((bits >> 9) | 0x3f800000u) - 1.0f;
    float u = f * 2.0f + lo;  // f*2 exact; single-rounded add matches XLA
    u = fmaxf(lo, u);
    float z = 1.41421356237f * xla_erfinv(u);  // sqrt(2) in f32

    float sv = (sc[d] - mn) / denom;
    float pv = sv + z * 0.05f;

    if (pv > v[0]) {  // strict > keeps lower index on ties, same as stable top_k
      bool done = false;
#pragma unroll
      for (int t = 0; t < 15; ++t) {
        if (!done) {
          if (pv > v[t + 1]) { v[t] = v[t + 1]; ix[t] = ix[t + 1]; }
          else               { v[t] = pv;      ix[t] = d; done = true; }
        }
      }
      if (!done) { v[15] = pv; ix[15] = d; }
    }
  }

  // rank by ascending index (the jnp.sort(idx) step), histogram
  uint32_t* cb = counts + b * (16 * DDIM);
#pragma unroll
  for (int jj = 0; jj < 16; ++jj) {
    int r = 0;
#pragma unroll
    for (int l = 0; l < 16; ++l) r += (ix[l] < ix[jj]) ? 1 : 0;
    atomicAdd(&cb[(r << 8) + ix[jj]], 1u);
  }
}

// grid: (16 p-tiles, 3 c, 128 bk); block 256 = 2 rows x 128 q, 4 rows/thread
__global__ void __launch_bounds__(256) patches_kernel(const float* __restrict__ x,
                                                      const uint32_t* __restrict__ counts,
                                                      float* __restrict__ out) {
  const int bk = blockIdx.z;          // b*16 + k
  const int b  = bk >> 4;
  const int c  = blockIdx.y;
  const int p0 = blockIdx.x << 3;     // 8 rows per block

  __shared__ float wlds[DDIM];
  const int tid = threadIdx.x;
  wlds[tid] = (float)counts[(bk << 8) + tid] / 500.0f;  // indicator mean
  __syncthreads();

  const int q  = tid & 127;
  const int pr = tid >> 7;  // 0..1

  float acc0 = 0.f, acc1 = 0.f, acc2 = 0.f, acc3 = 0.f;
  const float* xim = x + ((size_t)(b * 3 + c) << 20);  // 1024*1024 plane

  for (int iw = 0; iw < DDIM; ++iw) {
    float wv = wlds[iw];
    if (wv == 0.0f) continue;  // block-uniform branch
    int i = iw >> 4, w = iw & 15;
    int xq = (w << 6) + q - 32;
    bool qok = (xq >= 0) && (xq < 1024);
    int ybase = (i << 6) + p0 - 32 + pr;

    int y0 = ybase + 0, y1 = ybase + 2, y2 = ybase + 4, y3 = ybase + 6;
    float x0 = (qok && y0 >= 0 && y0 < 1024) ? xim[(size_t)y0 * 1024 + xq] : 0.0f;
    float x1 = (qok && y1 >= 0 && y1 < 1024) ? xim[(size_t)y1 * 1024 + xq] : 0.0f;
    float x2 = (qok && y2 >= 0 && y2 < 1024) ? xim[(size_t)y2 * 1024 + xq] : 0.0f;
    float x3 = (qok && y3 >= 0 && y3 < 1024) ? xim[(size_t)y3 * 1024 + xq] : 0.0f;
    acc0 += wv * x0;
    acc1 += wv * x1;
    acc2 += wv * x2;
    acc3 += wv * x3;
  }

  size_t obase = (((size_t)bk * 3 + c) * 128) * 128;
  out[obase + (size_t)(p0 + pr + 0) * 128 + q] = acc0;
  out[obase + (size_t)(p0 + pr + 2) * 128 + q] = acc1;
  out[obase + (size_t)(p0 + pr + 4) * 128 + q] = acc2;
  out[obase + (size_t)(p0 + pr + 6) * 128 + q] = acc3;
}

extern "C" void kernel_launch(void* const* d_in, const int* in_sizes, int n_in,
                              void* d_out, int out_size, void* d_ws, size_t ws_size,
                              hipStream_t stream) {
  const float* x_high = (const float*)d_in[0];
  const float* scores = (const float*)d_in[1];
  float* out = (float*)d_out;
  uint32_t* counts = (uint32_t*)d_ws;  // 8*16*256 u32 = 128 KB

  zero_counts<<<128, 256, 0, stream>>>(counts, 8 * 16 * DDIM);
  topk_kernel<<<(8 * NSAMP + 63) / 64, 64, 0, stream>>>(scores, counts);
  patches_kernel<<<dim3(16, 3, 128), 256, 0, stream>>>(x_high, counts, out);
}

// Round 2
// 221.757 us; speedup vs baseline: 1.8856x; 1.8856x over previous
//
#include <hip/hip_runtime.h>
#include <stdint.h>

// DPS_55336358642719
// in[0]: x_high  (8,3,1024,1024) f32
// in[1]: scores  (8,16,16)       f32
// out:   patches (128,3,128,128) f32
//
// ws layout: counts[8][16][256] as uint32  (131072 bytes)

#define NSAMP 500
#define DDIM  256

// ---------------- threefry2x32 (JAX-exact, key = seed 42) ----------------
__device__ __forceinline__ void threefry2x32_0_42(uint32_t x0, uint32_t x1,
                                                  uint32_t& o0, uint32_t& o1) {
  const uint32_t k0 = 0u, k1 = 42u;
  const uint32_t k2 = k0 ^ k1 ^ 0x1BD11BDAu;
  x0 += k0; x1 += k1;
#define TF_ROUND(r) { x0 += x1; x1 = (x1 << (r)) | (x1 >> (32 - (r))); x1 ^= x0; }
  TF_ROUND(13) TF_ROUND(15) TF_ROUND(26) TF_ROUND(6)
  x0 += k1; x1 += k2 + 1u;
  TF_ROUND(17) TF_ROUND(29) TF_ROUND(16) TF_ROUND(24)
  x0 += k2; x1 += k0 + 2u;
  TF_ROUND(13) TF_ROUND(15) TF_ROUND(26) TF_ROUND(6)
  x0 += k0; x1 += k1 + 3u;
  TF_ROUND(17) TF_ROUND(29) TF_ROUND(16) TF_ROUND(24)
  x0 += k1; x1 += k2 + 4u;
  TF_ROUND(13) TF_ROUND(15) TF_ROUND(26) TF_ROUND(6)
  x0 += k2; x1 += k0 + 5u;
#undef TF_ROUND
  o0 = x0; o1 = x1;
}

// XLA's ErfInv32 (Giles polynomial), fp-contract off for fidelity
__device__ __forceinline__ float xla_erfinv(float x) {
#pragma clang fp contract(off)
  float w = -log1pf(-x * x);
  float p;
  if (w < 5.0f) {
    w = w - 2.5f;
    p = 2.81022636e-08f;
    p = 3.43273939e-07f + p * w;
    p = -3.5233877e-06f + p * w;
    p = -4.39150654e-06f + p * w;
    p = 0.00021858087f + p * w;
    p = -0.00125372503f + p * w;
    p = -0.00417768164f + p * w;
    p = 0.246640727f + p * w;
    p = 1.50140941f + p * w;
  } else {
    w = sqrtf(w) - 3.0f;
    p = -0.000200214257f;
    p = 0.000100950558f + p * w;
    p = 0.00134934322f + p * w;
    p = -0.00367342844f + p * w;
    p = 0.00573950773f + p * w;
    p = -0.0076224613f + p * w;
    p = 0.00943887047f + p * w;
    p = 1.00167406f + p * w;
    p = 2.83297682f + p * w;
  }
  return p * x;
}

// One block = one (b, sample). Thread d computes perturbed value for index d,
// then rank-selects via all-pairs compare in LDS; histogram via atomics.
__global__ void __launch_bounds__(256) topk_kernel(const float* __restrict__ scores,
                                                   uint32_t* __restrict__ counts) {
#pragma clang fp contract(off)
  const int gs = blockIdx.x;          // b*NSAMP + n
  const int b = gs / NSAMP;
  const int n = gs - b * NSAMP;
  const int d = threadIdx.x;

  __shared__ float redmx[DDIM];
  __shared__ float redmn[DDIM];
  __shared__ float pvs[DDIM];
  __shared__ int wtot[4];

  const float sc = scores[b * DDIM + d];

  // block min/max of scores
  redmx[d] = sc; redmn[d] = sc;
  __syncthreads();
  for (int s = 128; s > 0; s >>= 1) {
    if (d < s) {
      redmx[d] = fmaxf(redmx[d], redmx[d + s]);
      redmn[d] = fminf(redmn[d], redmn[d + s]);
    }
    __syncthreads();
  }
  const float mx = redmx[0], mn = redmn[0];
  const float denom = (mx - mn) + 1e-5f;

  // perturbed value for own index (identical expression order to the
  // previously-verified version)
  const uint32_t j = (uint32_t)(b * (NSAMP * DDIM) + n * DDIM + d);
  uint32_t o0, o1;
  threefry2x32_0_42(0u, j, o0, o1);
  const uint32_t bits = o0 ^ o1;
  const float flo = -0.99999994f;  // nextafter(-1,0) in f32
  float f = __uint_as_float((bits >> 9) | 0x3f800000u) - 1.0f;
  float u = f * 2.0f + flo;
  u = fmaxf(flo, u);
  const float z = 1.41421356237f * xla_erfinv(u);
  const float sv = (sc - mn) / denom;
  const float pv = sv + z * 0.05f;

  pvs[d] = pv;
  __syncthreads();

  // rank = #{pv[e] > pv[d]} + #{e<d : pv[e]==pv[d]}  (top_k tie-break)
  const float4* pv4 = (const float4*)pvs;
  int gc = 0, eqb = 0;
  for (int e4 = 0; e4 < DDIM / 4; ++e4) {
    float4 o = pv4[e4];   // broadcast read, conflict-free
    int e = e4 << 2;
    gc += (o.x > pv); gc += (o.y > pv); gc += (o.z > pv); gc += (o.w > pv);
    eqb += (o.x == pv) & ((e + 0) < d);
    eqb += (o.y == pv) & ((e + 1) < d);
    eqb += (o.z == pv) & ((e + 2) < d);
    eqb += (o.w == pv) & ((e + 3) < d);
  }
  const bool sel = (gc + eqb) < 16;

  // rank among selected, ordered by ascending index (the jnp.sort step)
  const unsigned long long m = __ballot(sel);
  const int lane = d & 63, wv = d >> 6;
  if (lane == 0) wtot[wv] = __popcll(m);
  __syncthreads();
  int r = __popcll(m & ((1ull << lane) - 1ull));
  for (int w2 = 0; w2 < wv; ++w2) r += wtot[w2];

  if (sel) atomicAdd(&counts[(b << 12) + (r << 8) + d], 1u);
}

// grid: (16 p-tiles, 3 c, 8 b * 2 kgroups); block 256 = 2 rows x 128 q.
// Each block computes 8 k-outputs for an 8-row tile, loading each x row
// segment once and FMA-ing into 8 accumulators.
__global__ void __launch_bounds__(256) patches_kernel(const float* __restrict__ x,
                                                      const uint32_t* __restrict__ counts,
                                                      float* __restrict__ out) {
  const int p0 = blockIdx.x << 3;     // 8 rows per block
  const int c  = blockIdx.y;
  const int zb = blockIdx.z;          // b*2 + kg
  const int b  = zb >> 1;
  const int k0 = (zb & 1) << 3;       // 0 or 8

  __shared__ float wlds[8 * DDIM];    // weights for this k-group
  __shared__ float umask[DDIM];       // union support over the 8 k's
  const int tid = threadIdx.x;

  for (int t = tid; t < 8 * DDIM; t += 256) {
    int kk = t >> 8, d = t & 255;
    wlds[t] = (float)counts[((b * 16 + k0 + kk) << 8) + d] / 500.0f;
  }
  __syncthreads();
  {
    float mval = 0.0f;
#pragma unroll
    for (int kk = 0; kk < 8; ++kk) mval = fmaxf(mval, wlds[(kk << 8) + tid]);
    umask[tid] = mval;
  }
  __syncthreads();

  const int q  = tid & 127;
  const int pr = tid >> 7;            // 0..1; rows pr, pr+2, pr+4, pr+6

  float acc[8][4];
#pragma unroll
  for (int kk = 0; kk < 8; ++kk)
#pragma unroll
    for (int r = 0; r < 4; ++r) acc[kk][r] = 0.0f;

  const float* xim = x + ((size_t)(b * 3 + c) << 20);  // 1024*1024 plane

  for (int iw = 0; iw < DDIM; ++iw) {
    if (umask[iw] == 0.0f) continue;  // block-uniform skip
    const int i = iw >> 4, w = iw & 15;
    const int xq = (w << 6) + q - 32;
    const bool qok = (xq >= 0) && (xq < 1024);
    const int ybase = (i << 6) + p0 - 32 + pr;

    float xv[4];
#pragma unroll
    for (int r = 0; r < 4; ++r) {
      int y = ybase + 2 * r;
      xv[r] = (qok && y >= 0 && y < 1024) ? xim[(size_t)y * 1024 + xq] : 0.0f;
    }
#pragma unroll
    for (int kk = 0; kk < 8; ++kk) {
      float wv = wlds[(kk << 8) + iw];  // broadcast
      acc[kk][0] += wv * xv[0];
      acc[kk][1] += wv * xv[1];
      acc[kk][2] += wv * xv[2];
      acc[kk][3] += wv * xv[3];
    }
  }

#pragma unroll
  for (int kk = 0; kk < 8; ++kk) {
    const size_t obase = ((size_t)((b * 16 + k0 + kk) * 3 + c)) << 14;  // 128*128
#pragma unroll
    for (int r = 0; r < 4; ++r)
      out[obase + (size_t)(p0 + pr + 2 * r) * 128 + q] = acc[kk][r];
  }
}

extern "C" void kernel_launch(void* const* d_in, const int* in_sizes, int n_in,
                              void* d_out, int out_size, void* d_ws, size_t ws_size,
                              hipStream_t stream) {
  const float* x_high = (const float*)d_in[0];
  const float* scores = (const float*)d_in[1];
  float* out = (float*)d_out;
  uint32_t* counts = (uint32_t*)d_ws;  // 8*16*256 u32 = 128 KB

  hipMemsetAsync(counts, 0, 8 * 16 * DDIM * sizeof(uint32_t), stream);
  topk_kernel<<<8 * NSAMP, 256, 0, stream>>>(scores, counts);
  patches_kernel<<<dim3(16, 3, 16), 256, 0, stream>>>(x_high, counts, out);
}

// Round 4
// 198.573 us; speedup vs baseline: 2.1057x; 1.1168x over previous
//
#include <hip/hip_runtime.h>
#include <stdint.h>

// DPS_55336358642719  (round-4 resubmission of round-3 kernel — container
// acquisition failed last round; no kernel-side change needed)
// in[0]: x_high  (8,3,1024,1024) f32
// in[1]: scores  (8,16,16)       f32
// out:   patches (128,3,128,128) f32
//
// ws layout: counts[8][16][256] as uint32  (131072 bytes)

#define NSAMP 500
#define DDIM  256

// ---------------- threefry2x32 (JAX-exact, key = seed 42) ----------------
__device__ __forceinline__ void threefry2x32_0_42(uint32_t x0, uint32_t x1,
                                                  uint32_t& o0, uint32_t& o1) {
  const uint32_t k0 = 0u, k1 = 42u;
  const uint32_t k2 = k0 ^ k1 ^ 0x1BD11BDAu;
  x0 += k0; x1 += k1;
#define TF_ROUND(r) { x0 += x1; x1 = (x1 << (r)) | (x1 >> (32 - (r))); x1 ^= x0; }
  TF_ROUND(13) TF_ROUND(15) TF_ROUND(26) TF_ROUND(6)
  x0 += k1; x1 += k2 + 1u;
  TF_ROUND(17) TF_ROUND(29) TF_ROUND(16) TF_ROUND(24)
  x0 += k2; x1 += k0 + 2u;
  TF_ROUND(13) TF_ROUND(15) TF_ROUND(26) TF_ROUND(6)
  x0 += k0; x1 += k1 + 3u;
  TF_ROUND(17) TF_ROUND(29) TF_ROUND(16) TF_ROUND(24)
  x0 += k1; x1 += k2 + 4u;
  TF_ROUND(13) TF_ROUND(15) TF_ROUND(26) TF_ROUND(6)
  x0 += k2; x1 += k0 + 5u;
#undef TF_ROUND
  o0 = x0; o1 = x1;
}

// XLA's ErfInv32 (Giles polynomial), fp-contract off for fidelity
__device__ __forceinline__ float xla_erfinv(float x) {
#pragma clang fp contract(off)
  float w = -log1pf(-x * x);
  float p;
  if (w < 5.0f) {
    w = w - 2.5f;
    p = 2.81022636e-08f;
    p = 3.43273939e-07f + p * w;
    p = -3.5233877e-06f + p * w;
    p = -4.39150654e-06f + p * w;
    p = 0.00021858087f + p * w;
    p = -0.00125372503f + p * w;
    p = -0.00417768164f + p * w;
    p = 0.246640727f + p * w;
    p = 1.50140941f + p * w;
  } else {
    w = sqrtf(w) - 3.0f;
    p = -0.000200214257f;
    p = 0.000100950558f + p * w;
    p = 0.00134934322f + p * w;
    p = -0.00367342844f + p * w;
    p = 0.00573950773f + p * w;
    p = -0.0076224613f + p * w;
    p = 0.00943887047f + p * w;
    p = 1.00167406f + p * w;
    p = 2.83297682f + p * w;
  }
  return p * x;
}

// One block = one (b, sample). Thread d computes perturbed value for index d,
// then rank-selects via all-pairs compare in LDS; histogram via atomics.
__global__ void __launch_bounds__(256) topk_kernel(const float* __restrict__ scores,
                                                   uint32_t* __restrict__ counts) {
#pragma clang fp contract(off)
  const int gs = blockIdx.x;          // b*NSAMP + n
  const int b = gs / NSAMP;
  const int n = gs - b * NSAMP;
  const int d = threadIdx.x;
  const int lane = d & 63, wv = d >> 6;

  __shared__ float pvs[DDIM];
  __shared__ float wmx[4], wmn[4];
  __shared__ int wtot[4];

  const float sc = scores[b * DDIM + d];

  // block min/max of scores: wave shuffles + tiny LDS combine (exact ops)
  float mx = sc, mn = sc;
  for (int off = 32; off > 0; off >>= 1) {
    mx = fmaxf(mx, __shfl_xor(mx, off));
    mn = fminf(mn, __shfl_xor(mn, off));
  }
  if (lane == 0) { wmx[wv] = mx; wmn[wv] = mn; }
  __syncthreads();
  mx = fmaxf(fmaxf(wmx[0], wmx[1]), fmaxf(wmx[2], wmx[3]));
  mn = fminf(fminf(wmn[0], wmn[1]), fminf(wmn[2], wmn[3]));
  const float denom = (mx - mn) + 1e-5f;

  // perturbed value for own index (bit-identical expression order)
  const uint32_t j = (uint32_t)(b * (NSAMP * DDIM) + n * DDIM + d);
  uint32_t o0, o1;
  threefry2x32_0_42(0u, j, o0, o1);
  const uint32_t bits = o0 ^ o1;
  const float flo = -0.99999994f;  // nextafter(-1,0) in f32
  float f = __uint_as_float((bits >> 9) | 0x3f800000u) - 1.0f;
  float u = f * 2.0f + flo;
  u = fmaxf(flo, u);
  const float z = 1.41421356237f * xla_erfinv(u);
  const float sv = (sc - mn) / denom;
  const float pv = sv + z * 0.05f;

  pvs[d] = pv;
  __syncthreads();

  // rank = #{pv[e] > pv[d]} + #{e<d : pv[e]==pv[d]}  (top_k tie-break)
  const float4* pv4 = (const float4*)pvs;
  int gc = 0, eqb = 0;
  for (int e4 = 0; e4 < DDIM / 4; ++e4) {
    float4 o = pv4[e4];   // broadcast read, conflict-free
    int e = e4 << 2;
    gc += (o.x > pv); gc += (o.y > pv); gc += (o.z > pv); gc += (o.w > pv);
    eqb += (o.x == pv) & ((e + 0) < d);
    eqb += (o.y == pv) & ((e + 1) < d);
    eqb += (o.z == pv) & ((e + 2) < d);
    eqb += (o.w == pv) & ((e + 3) < d);
  }
  const bool sel = (gc + eqb) < 16;

  // rank among selected, ordered by ascending index (the jnp.sort step)
  const unsigned long long m = __ballot(sel);
  if (lane == 0) wtot[wv] = __popcll(m);
  __syncthreads();
  int r = __popcll(m & ((1ull << lane) - 1ull));
  for (int w2 = 0; w2 < wv; ++w2) r += wtot[w2];

  if (sel) atomicAdd(&counts[(b << 12) + (r << 8) + d], 1u);
}

// grid: (16 p-tiles, 3 c, 8 b * 2 kgroups); block 256 = 32 q-groups x 8 rows.
// Thread: one float4 of q x one row-slot x 8 k accumulators.
// Active weight columns compacted to a list; weights transposed in LDS so
// each iteration is 1 float4 global load + 2 ds_read_b128 + 32 FMA.
__global__ void __launch_bounds__(256) patches_kernel(const float* __restrict__ x,
                                                      const uint32_t* __restrict__ counts,
                                                      float* __restrict__ out) {
  const int p0 = blockIdx.x << 3;     // 8 rows per block
  const int c  = blockIdx.y;
  const int zb = blockIdx.z;          // b*2 + kg
  const int b  = zb >> 1;
  const int k0 = (zb & 1) << 3;       // 0 or 8

  __shared__ __align__(16) float wlds[DDIM * 8];  // [d][k] transposed
  __shared__ int collist[DDIM];
  __shared__ int wcnt[4];

  const int tid = threadIdx.x;
  const int lane = tid & 63, wvi = tid >> 6;

  // load weights (coalesced per k), build transposed layout + active flag
  {
    bool any = false;
#pragma unroll
    for (int kk = 0; kk < 8; ++kk) {
      float w = (float)counts[((b * 16 + k0 + kk) << 8) + tid] / 500.0f;
      wlds[tid * 8 + kk] = w;
      any = any || (w != 0.0f);
    }
    // compact active column indices (ascending — preserves sum order)
    unsigned long long m = __ballot(any);
    if (lane == 0) wcnt[wvi] = __popcll(m);
    __syncthreads();
    int base = 0;
    for (int w2 = 0; w2 < wvi; ++w2) base += wcnt[w2];
    if (any) {
      int pos = base + __popcll(m & ((1ull << lane) - 1ull));
      collist[pos] = tid;
    }
    __syncthreads();
  }
  const int nact = wcnt[0] + wcnt[1] + wcnt[2] + wcnt[3];

  const int q0   = (tid & 31) << 2;   // 0,4,...,124
  const int slot = tid >> 5;          // 0..7

  float4 acc[8];
#pragma unroll
  for (int kk = 0; kk < 8; ++kk) acc[kk] = make_float4(0.f, 0.f, 0.f, 0.f);

  const float* xim = x + ((size_t)(b * 3 + c) << 20);  // 1024*1024 plane

  for (int it = 0; it < nact; ++it) {
    const int iw = collist[it];       // LDS broadcast
    const int i = iw >> 4, w = iw & 15;
    const int xq0 = (w << 6) + q0 - 32;
    const int y   = (i << 6) + p0 + slot - 32;
    // float4 groups are 4-aligned so they're wholly in or out of bounds
    const bool ok = (xq0 >= 0) & (xq0 <= 1020) & (y >= 0) & (y < 1024);

    float4 xv = make_float4(0.f, 0.f, 0.f, 0.f);
    if (ok) xv = *(const float4*)(xim + ((size_t)y << 10) + xq0);

    const float4 wa = *(const float4*)&wlds[iw * 8 + 0];  // ds_read_b128
    const float4 wb = *(const float4*)&wlds[iw * 8 + 4];  // ds_read_b128

#define ACC_K(kk, wv_)                                            \
    { acc[kk].x += (wv_) * xv.x; acc[kk].y += (wv_) * xv.y;       \
      acc[kk].z += (wv_) * xv.z; acc[kk].w += (wv_) * xv.w; }
    ACC_K(0, wa.x) ACC_K(1, wa.y) ACC_K(2, wa.z) ACC_K(3, wa.w)
    ACC_K(4, wb.x) ACC_K(5, wb.y) ACC_K(6, wb.z) ACC_K(7, wb.w)
#undef ACC_K
  }

#pragma unroll
  for (int kk = 0; kk < 8; ++kk) {
    const size_t obase = ((size_t)((b * 16 + k0 + kk) * 3 + c)) << 14;  // 128*128
    float4* dst = (float4*)(out + obase + (size_t)(p0 + slot) * 128 + q0);
    __builtin_nontemporal_store(acc[kk].x, &dst->x);
    __builtin_nontemporal_store(acc[kk].y, &dst->y);
    __builtin_nontemporal_store(acc[kk].z, &dst->z);
    __builtin_nontemporal_store(acc[kk].w, &dst->w);
  }
}

extern "C" void kernel_launch(void* const* d_in, const int* in_sizes, int n_in,
                              void* d_out, int out_size, void* d_ws, size_t ws_size,
                              hipStream_t stream) {
  const float* x_high = (const float*)d_in[0];
  const float* scores = (const float*)d_in[1];
  float* out = (float*)d_out;
  uint32_t* counts = (uint32_t*)d_ws;  // 8*16*256 u32 = 128 KB

  hipMemsetAsync(counts, 0, 8 * 16 * DDIM * sizeof(uint32_t), stream);
  topk_kernel<<<8 * NSAMP, 256, 0, stream>>>(scores, counts);
  patches_kernel<<<dim3(16, 3, 16), 256, 0, stream>>>(x_high, counts, out);
}

// Round 6
// 197.057 us; speedup vs baseline: 2.1219x; 1.0077x over previous
//
#include <hip/hip_runtime.h>
#include <stdint.h>

// DPS_55336358642719  (round-6 resubmission of round-5 kernel — harness
// Trio-nursery failure last round; kernel never executed)
// in[0]: x_high  (8,3,1024,1024) f32
// in[1]: scores  (8,16,16)       f32
// out:   patches (128,3,128,128) f32
//
// ws layout: counts[8][16][256] as uint32  (131072 bytes)
//
// NOTE: measured harness floor is ~145 us of fillBufferAligned re-poison
// (402 MB @ ~84% HBM peak) per timed iteration — not addressable from here.

#define NSAMP 500
#define DDIM  256

// ---------------- threefry2x32 (JAX-exact, key = seed 42) ----------------
__device__ __forceinline__ void threefry2x32_0_42(uint32_t x0, uint32_t x1,
                                                  uint32_t& o0, uint32_t& o1) {
  const uint32_t k0 = 0u, k1 = 42u;
  const uint32_t k2 = k0 ^ k1 ^ 0x1BD11BDAu;
  x0 += k0; x1 += k1;
#define TF_ROUND(r) { x0 += x1; x1 = (x1 << (r)) | (x1 >> (32 - (r))); x1 ^= x0; }
  TF_ROUND(13) TF_ROUND(15) TF_ROUND(26) TF_ROUND(6)
  x0 += k1; x1 += k2 + 1u;
  TF_ROUND(17) TF_ROUND(29) TF_ROUND(16) TF_ROUND(24)
  x0 += k2; x1 += k0 + 2u;
  TF_ROUND(13) TF_ROUND(15) TF_ROUND(26) TF_ROUND(6)
  x0 += k0; x1 += k1 + 3u;
  TF_ROUND(17) TF_ROUND(29) TF_ROUND(16) TF_ROUND(24)
  x0 += k1; x1 += k2 + 4u;
  TF_ROUND(13) TF_ROUND(15) TF_ROUND(26) TF_ROUND(6)
  x0 += k2; x1 += k0 + 5u;
#undef TF_ROUND
  o0 = x0; o1 = x1;
}

// XLA's ErfInv32 (Giles polynomial), fp-contract off for fidelity
__device__ __forceinline__ float xla_erfinv(float x) {
#pragma clang fp contract(off)
  float w = -log1pf(-x * x);
  float p;
  if (w < 5.0f) {
    w = w - 2.5f;
    p = 2.81022636e-08f;
    p = 3.43273939e-07f + p * w;
    p = -3.5233877e-06f + p * w;
    p = -4.39150654e-06f + p * w;
    p = 0.00021858087f + p * w;
    p = -0.00125372503f + p * w;
    p = -0.00417768164f + p * w;
    p = 0.246640727f + p * w;
    p = 1.50140941f + p * w;
  } else {
    w = sqrtf(w) - 3.0f;
    p = -0.000200214257f;
    p = 0.000100950558f + p * w;
    p = 0.00134934322f + p * w;
    p = -0.00367342844f + p * w;
    p = 0.00573950773f + p * w;
    p = -0.0076224613f + p * w;
    p = 0.00943887047f + p * w;
    p = 1.00167406f + p * w;
    p = 2.83297682f + p * w;
  }
  return p * x;
}

// One block = one (b, sample). Thread d computes perturbed value for index d,
// then rank-selects via all-pairs compare in LDS; histogram via atomics.
__global__ void __launch_bounds__(256) topk_kernel(const float* __restrict__ scores,
                                                   uint32_t* __restrict__ counts) {
#pragma clang fp contract(off)
  const int gs = blockIdx.x;          // b*NSAMP + n
  const int b = gs / NSAMP;
  const int n = gs - b * NSAMP;
  const int d = threadIdx.x;
  const int lane = d & 63, wv = d >> 6;

  __shared__ float pvs[DDIM];
  __shared__ float wmx[4], wmn[4];
  __shared__ int wtot[4];

  const float sc = scores[b * DDIM + d];

  // block min/max of scores: wave shuffles + tiny LDS combine (exact ops)
  float mx = sc, mn = sc;
  for (int off = 32; off > 0; off >>= 1) {
    mx = fmaxf(mx, __shfl_xor(mx, off));
    mn = fminf(mn, __shfl_xor(mn, off));
  }
  if (lane == 0) { wmx[wv] = mx; wmn[wv] = mn; }
  __syncthreads();
  mx = fmaxf(fmaxf(wmx[0], wmx[1]), fmaxf(wmx[2], wmx[3]));
  mn = fminf(fminf(wmn[0], wmn[1]), fminf(wmn[2], wmn[3]));
  const float denom = (mx - mn) + 1e-5f;

  // perturbed value for own index (bit-identical expression order)
  const uint32_t j = (uint32_t)(b * (NSAMP * DDIM) + n * DDIM + d);
  uint32_t o0, o1;
  threefry2x32_0_42(0u, j, o0, o1);
  const uint32_t bits = o0 ^ o1;
  const float flo = -0.99999994f;  // nextafter(-1,0) in f32
  float f = __uint_as_float((bits >> 9) | 0x3f800000u) - 1.0f;
  float u = f * 2.0f + flo;
  u = fmaxf(flo, u);
  const float z = 1.41421356237f * xla_erfinv(u);
  const float sv = (sc - mn) / denom;
  const float pv = sv + z * 0.05f;

  pvs[d] = pv;
  __syncthreads();

  // rank = #{pv[e] > pv[d]} + #{e<d : pv[e]==pv[d]}  (top_k tie-break)
  const float4* pv4 = (const float4*)pvs;
  int gc = 0, eqb = 0;
  for (int e4 = 0; e4 < DDIM / 4; ++e4) {
    float4 o = pv4[e4];   // broadcast read, conflict-free
    int e = e4 << 2;
    gc += (o.x > pv); gc += (o.y > pv); gc += (o.z > pv); gc += (o.w > pv);
    eqb += (o.x == pv) & ((e + 0) < d);
    eqb += (o.y == pv) & ((e + 1) < d);
    eqb += (o.z == pv) & ((e + 2) < d);
    eqb += (o.w == pv) & ((e + 3) < d);
  }
  const bool sel = (gc + eqb) < 16;

  // rank among selected, ordered by ascending index (the jnp.sort step)
  const unsigned long long m = __ballot(sel);
  if (lane == 0) wtot[wv] = __popcll(m);
  __syncthreads();
  int r = __popcll(m & ((1ull << lane) - 1ull));
  for (int w2 = 0; w2 < wv; ++w2) r += wtot[w2];

  if (sel) atomicAdd(&counts[(b << 12) + (r << 8) + d], 1u);
}

// grid: (16 p-tiles, 3 c, 8 b * 2 kgroups); block 256 = 32 q-groups x 8 rows.
// Branchless bounds (precomputed 16-bit masks), compacted weights+offsets,
// 1-deep software prefetch of the x float4.
__global__ void __launch_bounds__(256) patches_kernel(const float* __restrict__ x,
                                                      const uint32_t* __restrict__ counts,
                                                      float* __restrict__ out) {
  const int p0 = blockIdx.x << 3;     // 8 rows per block
  const int c  = blockIdx.y;
  const int zb = blockIdx.z;          // b*2 + kg
  const int b  = zb >> 1;
  const int k0 = (zb & 1) << 3;       // 0 or 8

  __shared__ __align__(16) float cw[DDIM * 8];  // compacted [pos][k]
  __shared__ int colOff[DDIM];                  // compacted i*65536 + w*64
  __shared__ int wcnt[4];

  const int tid = threadIdx.x;
  const int lane = tid & 63, wvi = tid >> 6;

  // load weights (coalesced per k), compact active columns ascending
  {
    float wreg[8];
    bool any = false;
#pragma unroll
    for (int kk = 0; kk < 8; ++kk) {
      float w = (float)counts[((b * 16 + k0 + kk) << 8) + tid] / 500.0f;
      wreg[kk] = w;
      any = any || (w != 0.0f);
    }
    unsigned long long m = __ballot(any);
    if (lane == 0) wcnt[wvi] = __popcll(m);
    __syncthreads();
    int base = 0;
    for (int w2 = 0; w2 < wvi; ++w2) base += wcnt[w2];
    if (any) {
      int pos = base + __popcll(m & ((1ull << lane) - 1ull));
      colOff[pos] = ((tid >> 4) << 16) | ((tid & 15) << 6);  // i*65536 + w*64
#pragma unroll
      for (int kk = 0; kk < 8; ++kk) cw[pos * 8 + kk] = wreg[kk];
    }
    __syncthreads();
  }
  const int nact = wcnt[0] + wcnt[1] + wcnt[2] + wcnt[3];

  const int q0   = (tid & 31) << 2;   // 0,4,...,124
  const int slot = tid >> 5;          // 0..7
  const int ps   = p0 + slot;

  // bounds masks: bit w of qm / bit i of ym says the float4 is in-bounds
  int qm = 0xFFFF, ym = 0xFFFF;
  if (q0 < 32) qm &= ~1;
  if (q0 > 92) qm &= ~0x8000;
  if (ps < 32) ym &= ~1;
  if (ps > 95) ym &= ~0x8000;
  const int baseOff = (ps - 32) * 1024 + q0 - 32;  // add colOff -> x offset

  float4 acc[8];
#pragma unroll
  for (int kk = 0; kk < 8; ++kk) acc[kk] = make_float4(0.f, 0.f, 0.f, 0.f);

  const float* xim = x + ((size_t)(b * 3 + c) << 20);  // 1024*1024 plane

  float4 xv = make_float4(0.f, 0.f, 0.f, 0.f);
  int okc = 0;
  if (nact > 0) {
    const int co = colOff[0];
    okc = (qm >> ((co >> 6) & 15)) & (ym >> (co >> 16)) & 1;
    xv = *(const float4*)(xim + (okc ? (baseOff + co) : 0));
  }

  for (int it = 0; it < nact; ++it) {
    // issue next x load before this iteration's FMAs (1-deep prefetch)
    const int itn = (it + 1 < nact) ? it + 1 : it;
    const int con = colOff[itn];
    const int okn = (qm >> ((con >> 6) & 15)) & (ym >> (con >> 16)) & 1;
    const float4 xn = *(const float4*)(xim + (okn ? (baseOff + con) : 0));

    float4 xc = xv;
    xc.x = okc ? xc.x : 0.0f;
    xc.y = okc ? xc.y : 0.0f;
    xc.z = okc ? xc.z : 0.0f;
    xc.w = okc ? xc.w : 0.0f;

    const float4 wa = *(const float4*)&cw[it * 8 + 0];  // ds_read_b128
    const float4 wb = *(const float4*)&cw[it * 8 + 4];  // ds_read_b128

#define ACC_K(kk, wv_)                                            \
    { acc[kk].x += (wv_) * xc.x; acc[kk].y += (wv_) * xc.y;       \
      acc[kk].z += (wv_) * xc.z; acc[kk].w += (wv_) * xc.w; }
    ACC_K(0, wa.x) ACC_K(1, wa.y) ACC_K(2, wa.z) ACC_K(3, wa.w)
    ACC_K(4, wb.x) ACC_K(5, wb.y) ACC_K(6, wb.z) ACC_K(7, wb.w)
#undef ACC_K

    xv = xn;
    okc = okn;
  }

#pragma unroll
  for (int kk = 0; kk < 8; ++kk) {
    const size_t obase = ((size_t)((b * 16 + k0 + kk) * 3 + c)) << 14;  // 128*128
    float4* dst = (float4*)(out + obase + (size_t)ps * 128 + q0);
    __builtin_nontemporal_store(acc[kk].x, &dst->x);
    __builtin_nontemporal_store(acc[kk].y, &dst->y);
    __builtin_nontemporal_store(acc[kk].z, &dst->z);
    __builtin_nontemporal_store(acc[kk].w, &dst->w);
  }
}

extern "C" void kernel_launch(void* const* d_in, const int* in_sizes, int n_in,
                              void* d_out, int out_size, void* d_ws, size_t ws_size,
                              hipStream_t stream) {
  const float* x_high = (const float*)d_in[0];
  const float* scores = (const float*)d_in[1];
  float* out = (float*)d_out;
  uint32_t* counts = (uint32_t*)d_ws;  // 8*16*256 u32 = 128 KB

  hipMemsetAsync(counts, 0, 8 * 16 * DDIM * sizeof(uint32_t), stream);
  topk_kernel<<<8 * NSAMP, 256, 0, stream>>>(scores, counts);
  patches_kernel<<<dim3(16, 3, 16), 256, 0, stream>>>(x_high, counts, out);
}